// Round 5
// baseline (1052.127 us; speedup 1.0000x reference)
//
#include <hip/hip_runtime.h>
#include <math.h>
#include <float.h>

#define N_ROWS  65536
#define EDIM    256
#define NE      1024
#define BETA    0.25f
#define LAMBDA  0.99f
#define EPS     2.5e-4f

// ---------------- ws layout (float units) ----------------
// [0] loss_acc  [1] flag_cnt(int)  [64] e_sq[1024]
// [1088] counts[1024]
// [2048]   e_t[256*1024]
// [264192] B_hi (ushort[1024*256] = 131072 f)
// [395264] B_lo
// [526336] idx[65536] (int)
// [591872] flags[65536] (int)
// [657408] partial[65536*8] float4  (8 MB)
// total ~11.0 MB

#define O_ZQ   1
#define O_IDX  16777217
#define O_PERP 16842753
#define O_NT   16842754
#define O_MT   16843778

typedef short  bf16x8 __attribute__((ext_vector_type(8)));
typedef float  f32x4  __attribute__((ext_vector_type(4)));

__device__ __forceinline__ ushort f2bf(float x) {
    unsigned u = __float_as_uint(x);
    return (ushort)((u + 0x7FFFu + ((u >> 16) & 1u)) >> 16);
}
__device__ __forceinline__ float bf2f(ushort h) {
    return __uint_as_float(((unsigned)h) << 16);
}

// ---------------------------------------------------------------------------
// prep: e_t transpose, B_hi/B_lo split-bf16, zero accumulators
__global__ __launch_bounds__(64) void prep_kernel(const float* __restrict__ emb,
                                                  float* __restrict__ e_t,
                                                  ushort* __restrict__ Bhi,
                                                  ushort* __restrict__ Blo,
                                                  float* __restrict__ loss_acc,
                                                  int* __restrict__ flag_cnt) {
    int j = blockIdx.x, l = threadIdx.x;
    float4 v = ((const float4*)(emb + j * EDIM))[l];
    int k = 4 * l;
    e_t[(k + 0) * NE + j] = v.x;
    e_t[(k + 1) * NE + j] = v.y;
    e_t[(k + 2) * NE + j] = v.z;
    e_t[(k + 3) * NE + j] = v.w;
    float f[4] = {v.x, v.y, v.z, v.w};
    ushort h[4], lo[4];
    #pragma unroll
    for (int i = 0; i < 4; ++i) { h[i] = f2bf(f[i]); lo[i] = f2bf(f[i] - bf2f(h[i])); }
    uint2 ph = make_uint2((uint)h[0] | ((uint)h[1] << 16), (uint)h[2] | ((uint)h[3] << 16));
    uint2 pl = make_uint2((uint)lo[0] | ((uint)lo[1] << 16), (uint)lo[2] | ((uint)lo[3] << 16));
    *(uint2*)(Bhi + j * EDIM + k) = ph;
    *(uint2*)(Blo + j * EDIM + k) = pl;
    if (j == 0 && l == 0) { *loss_acc = 0.0f; *flag_cnt = 0; }
}

// ---------------------------------------------------------------------------
// sq_kernel: numpy-pairwise-exact fp32 sum of squares (row of 256)
__global__ __launch_bounds__(256) void sq_kernel(const float* __restrict__ src,
                                                 float* __restrict__ dst) {
    const int tid = threadIdx.x;
    const int row = blockIdx.x * 16 + (tid >> 4);
    const int q = tid & 15, h = q >> 3, j = q & 7;
    const float* __restrict__ p = src + (size_t)row * EDIM + h * 128 + j;
    float acc = __fmul_rn(p[0], p[0]);
    #pragma unroll
    for (int t = 1; t < 16; ++t) { float v = p[8 * t]; acc = __fadd_rn(acc, __fmul_rn(v, v)); }
    acc = __fadd_rn(acc, __shfl_xor(acc, 1));
    acc = __fadd_rn(acc, __shfl_xor(acc, 2));
    acc = __fadd_rn(acc, __shfl_xor(acc, 4));
    acc = __fadd_rn(acc, __shfl_xor(acc, 8));
    if (q == 0) dst[row] = acc;
}

// ---------------------------------------------------------------------------
__device__ __forceinline__ void merge2(float& v1, int& i1, float& v2, int& i2,
                                       float w1, int j1, float w2, int j2) {
    bool w1best = (w1 < v1) || (w1 == v1 && j1 < i1);
    if (w1best) {
        bool keep = (v1 < w2) || (v1 == w2 && i1 < j2);
        v2 = keep ? v1 : w2; i2 = keep ? i1 : j2;
        v1 = w1; i1 = j1;
    } else {
        bool rep = (w1 < v2) || (w1 == v2 && j1 < i2);
        if (rep) { v2 = w1; i2 = j1; }
    }
}
__device__ __forceinline__ void ins2(float& v1, int& i1, float& v2, int& i2,
                                     float s, int c) {
    if (s < v1 || (s == v1 && c < i1)) { v2 = v1; i2 = i1; v1 = s; i1 = c; }
    else if (s < v2 || (s == v2 && c < i2)) { v2 = s; i2 = c; }
}

// ---------------------------------------------------------------------------
// mfma_kernel: approx scores via split-bf16 MFMA. 128x128 tile, BK=32 (one
// MFMA K-step), 3 passes hh+hl+lh into one fp32 acc. Epilogue: per-row top-2
// over the block's 128 cols -> partial[row][nb].
#define BK  32
#define LDK 40
__global__ __launch_bounds__(256) void mfma_kernel(const float* __restrict__ z,
                                                   const ushort* __restrict__ Bhi,
                                                   const ushort* __restrict__ Blo,
                                                   const float* __restrict__ e_sq,
                                                   float4* __restrict__ partial) {
    __shared__ __align__(16) ushort sAh[128 * LDK], sAl[128 * LDK];
    __shared__ __align__(16) ushort sBh[128 * LDK], sBl[128 * LDK];
    const int tid = threadIdx.x;
    const int nb = blockIdx.x & 7, mb = blockIdx.x >> 3;
    const int row0 = mb * 128, col0 = nb * 128;
    const int wave = tid >> 6, lane = tid & 63;
    const int wr = wave >> 1, wc = wave & 1;
    const int lquad = lane >> 4, l16 = lane & 15;

    f32x4 acc[4][4];
    #pragma unroll
    for (int mi = 0; mi < 4; ++mi)
        #pragma unroll
        for (int ni = 0; ni < 4; ++ni) acc[mi][ni] = (f32x4)0.0f;

    for (int k0 = 0; k0 < EDIM; k0 += BK) {
        // ---- stage A (fp32 -> hi/lo bf16) ----
        {
            const int r = tid >> 1, hh = tid & 1;
            const float* src = z + (size_t)(row0 + r) * EDIM + k0 + hh * 16;
            ushort* dA_h = sAh + r * LDK + hh * 16;
            ushort* dA_l = sAl + r * LDK + hh * 16;
            #pragma unroll
            for (int g = 0; g < 2; ++g) {
                float4 f0 = ((const float4*)src)[2 * g];
                float4 f1 = ((const float4*)src)[2 * g + 1];
                float v[8] = {f0.x, f0.y, f0.z, f0.w, f1.x, f1.y, f1.z, f1.w};
                ushort h[8], lo[8];
                #pragma unroll
                for (int i = 0; i < 8; ++i) { h[i] = f2bf(v[i]); lo[i] = f2bf(v[i] - bf2f(h[i])); }
                uint4 H = make_uint4((uint)h[0] | ((uint)h[1] << 16), (uint)h[2] | ((uint)h[3] << 16),
                                     (uint)h[4] | ((uint)h[5] << 16), (uint)h[6] | ((uint)h[7] << 16));
                uint4 L = make_uint4((uint)lo[0] | ((uint)lo[1] << 16), (uint)lo[2] | ((uint)lo[3] << 16),
                                     (uint)lo[4] | ((uint)lo[5] << 16), (uint)lo[6] | ((uint)lo[7] << 16));
                ((uint4*)dA_h)[g] = H;
                ((uint4*)dA_l)[g] = L;
            }
        }
        // ---- stage B (already bf16) ----
        {
            const int q = tid & 3;
            #pragma unroll
            for (int it = 0; it < 2; ++it) {
                int n = (tid >> 2) + it * 64;
                size_t off = (size_t)(col0 + n) * EDIM + k0 + q * 8;
                *(uint4*)(sBh + n * LDK + q * 8) = *(const uint4*)(Bhi + off);
                *(uint4*)(sBl + n * LDK + q * 8) = *(const uint4*)(Blo + off);
            }
        }
        __syncthreads();

        bf16x8 ah[4], al[4], bh[4], bl[4];
        #pragma unroll
        for (int mi = 0; mi < 4; ++mi) {
            int m = wr * 64 + mi * 16 + l16;
            ah[mi] = *(const bf16x8*)(sAh + m * LDK + lquad * 8);
            al[mi] = *(const bf16x8*)(sAl + m * LDK + lquad * 8);
        }
        #pragma unroll
        for (int ni = 0; ni < 4; ++ni) {
            int n = wc * 64 + ni * 16 + l16;
            bh[ni] = *(const bf16x8*)(sBh + n * LDK + lquad * 8);
            bl[ni] = *(const bf16x8*)(sBl + n * LDK + lquad * 8);
        }
        #pragma unroll
        for (int mi = 0; mi < 4; ++mi)
            #pragma unroll
            for (int ni = 0; ni < 4; ++ni) {
                acc[mi][ni] = __builtin_amdgcn_mfma_f32_16x16x32_bf16(ah[mi], bh[ni], acc[mi][ni], 0, 0, 0);
                acc[mi][ni] = __builtin_amdgcn_mfma_f32_16x16x32_bf16(ah[mi], bl[ni], acc[mi][ni], 0, 0, 0);
                acc[mi][ni] = __builtin_amdgcn_mfma_f32_16x16x32_bf16(al[mi], bh[ni], acc[mi][ni], 0, 0, 0);
            }
        __syncthreads();
    }

    // ---- epilogue: s = esq - 2*dot ; per-row top-2 over the block's 128 cols ----
    float eq[4]; int cidx[4];
    #pragma unroll
    for (int ni = 0; ni < 4; ++ni) {
        cidx[ni] = col0 + wc * 64 + ni * 16 + l16;
        eq[ni] = e_sq[cidx[ni]];
    }
    float4* pt = (float4*)sAh;  // [2][128], 4 KB (LDS reuse after last sync)
    #pragma unroll
    for (int mi = 0; mi < 4; ++mi) {
        #pragma unroll
        for (int reg = 0; reg < 4; ++reg) {
            float v1 = FLT_MAX, v2 = FLT_MAX; int i1 = 0x7fffffff, i2 = 0x7fffffff;
            #pragma unroll
            for (int ni = 0; ni < 4; ++ni) {
                float s = fmaf(-2.0f, acc[mi][ni][reg], eq[ni]);
                ins2(v1, i1, v2, i2, s, cidx[ni]);
            }
            // C/D layout: col = lane&15, row = (lane>>4)*4 + reg (m89-verified)
            #pragma unroll
            for (int m = 1; m < 16; m <<= 1) {
                float w1 = __shfl_xor(v1, m), w2 = __shfl_xor(v2, m);
                int   j1 = __shfl_xor(i1, m), j2 = __shfl_xor(i2, m);
                merge2(v1, i1, v2, i2, w1, j1, w2, j2);
            }
            if (l16 == 0) {
                int row = wr * 64 + mi * 16 + lquad * 4 + reg;
                pt[wc * 128 + row] = make_float4(v1, v2, __int_as_float(i1), __int_as_float(i2));
            }
        }
    }
    __syncthreads();
    if (tid < 128) {
        float4 a = pt[tid], b = pt[128 + tid];
        float v1 = a.x, v2 = a.y; int i1 = __float_as_int(a.z), i2 = __float_as_int(a.w);
        merge2(v1, i1, v2, i2, b.x, __float_as_int(b.z), b.y, __float_as_int(b.w));
        partial[(size_t)(row0 + tid) * 8 + nb] = make_float4(v1, v2, __int_as_float(i1), __int_as_float(i2));
    }
}

// ---------------------------------------------------------------------------
// reduce: merge 8 partials per row -> provisional idx; flag rows with gap<EPS
__global__ __launch_bounds__(256) void reduce_kernel(const float4* __restrict__ partial,
                                                     int* __restrict__ idx_out,
                                                     int* __restrict__ flags,
                                                     int* __restrict__ flag_cnt) {
    int row = blockIdx.x * 256 + threadIdx.x;
    float4 p = partial[(size_t)row * 8];
    float v1 = p.x, v2 = p.y; int i1 = __float_as_int(p.z), i2 = __float_as_int(p.w);
    #pragma unroll
    for (int k = 1; k < 8; ++k) {
        float4 q = partial[(size_t)row * 8 + k];
        merge2(v1, i1, v2, i2, q.x, __float_as_int(q.z), q.y, __float_as_int(q.w));
    }
    idx_out[row] = i1;
    if (v2 - v1 < EPS) { int pos = atomicAdd(flag_cnt, 1); flags[pos] = row; }
}

// ---------------------------------------------------------------------------
// resolve: exact fp32 (numpy-semantics) full-row argmin for flagged rows
__global__ __launch_bounds__(256) void resolve_kernel(const float* __restrict__ z,
                                                      const float* __restrict__ e_t,
                                                      const float* __restrict__ e_sq,
                                                      const int* __restrict__ flags,
                                                      const int* __restrict__ flag_cnt,
                                                      int* __restrict__ idx_out) {
    __shared__ float zrow[EDIM];
    __shared__ float zsq_s;
    __shared__ float wv[4]; __shared__ int wi[4];
    const int tid = threadIdx.x, wave = tid >> 6, lane = tid & 63;
    const int cnt = *flag_cnt;
    for (int f = blockIdx.x; f < cnt; f += gridDim.x) {
        const int row = flags[f];
        __syncthreads();
        zrow[tid] = z[(size_t)row * EDIM + tid];
        __syncthreads();
        if (tid < 16) {   // numpy-pairwise-exact zsq
            const int h = tid >> 3, j = tid & 7;
            const float* p = zrow + h * 128 + j;
            float a = __fmul_rn(p[0], p[0]);
            #pragma unroll
            for (int t = 1; t < 16; ++t) { float v = p[8 * t]; a = __fadd_rn(a, __fmul_rn(v, v)); }
            a = __fadd_rn(a, __shfl_xor(a, 1));
            a = __fadd_rn(a, __shfl_xor(a, 2));
            a = __fadd_rn(a, __shfl_xor(a, 4));
            a = __fadd_rn(a, __shfl_xor(a, 8));
            if (tid == 0) zsq_s = a;
        }
        __syncthreads();
        const float zq = zsq_s;
        float acc[4] = {0.f, 0.f, 0.f, 0.f};
        for (int k = 0; k < EDIM; ++k) {           // sequential-k fma chain (R2-exact)
            float4 e = *(const float4*)(e_t + k * NE + 4 * tid);
            float zk = zrow[k];
            acc[0] = fmaf(zk, e.x, acc[0]);
            acc[1] = fmaf(zk, e.y, acc[1]);
            acc[2] = fmaf(zk, e.z, acc[2]);
            acc[3] = fmaf(zk, e.w, acc[3]);
        }
        float bv = FLT_MAX; int bi = 0x7fffffff;
        #pragma unroll
        for (int c = 0; c < 4; ++c) {
            int col = 4 * tid + c;
            float d = __fsub_rn(__fadd_rn(zq, e_sq[col]), __fmul_rn(2.0f, acc[c]));
            if (d < bv || (d == bv && col < bi)) { bv = d; bi = col; }
        }
        #pragma unroll
        for (int m = 1; m < 64; m <<= 1) {
            float v = __shfl_xor(bv, m); int i = __shfl_xor(bi, m);
            if (v < bv || (v == bv && i < bi)) { bv = v; bi = i; }
        }
        if (lane == 0) { wv[wave] = bv; wi[wave] = bi; }
        __syncthreads();
        if (tid == 0) {
            #pragma unroll
            for (int w = 1; w < 4; ++w)
                if (wv[w] < bv || (wv[w] == bv && wi[w] < bi)) { bv = wv[w]; bi = wi[w]; }
            idx_out[row] = bi;
        }
    }
}

// ---------------------------------------------------------------------------
__global__ __launch_bounds__(256) void gather_kernel(const float* __restrict__ z,
                                                     const float* __restrict__ emb,
                                                     const int* __restrict__ idx,
                                                     float* __restrict__ out_zq,
                                                     float* __restrict__ out_idx,
                                                     float* __restrict__ loss_acc) {
    int sub = threadIdx.x >> 6, lane = threadIdx.x & 63;
    int row = blockIdx.x * 4 + sub;
    int id = idx[row];
    float4 e = ((const float4*)(emb + (size_t)id * EDIM))[lane];
    float4 zv = ((const float4*)(z + (size_t)row * EDIM))[lane];
    float* o = out_zq + (size_t)row * EDIM + lane * 4;
    o[0] = e.x; o[1] = e.y; o[2] = e.z; o[3] = e.w;
    float dx = e.x - zv.x, dy = e.y - zv.y, dz = e.z - zv.z, dw = e.w - zv.w;
    float lp = dx * dx + dy * dy + dz * dz + dw * dw;
    #pragma unroll
    for (int m = 32; m; m >>= 1) lp += __shfl_down(lp, m);
    __shared__ float red[4];
    if (lane == 0) { red[sub] = lp; out_idx[row] = (float)id; }
    __syncthreads();
    if (threadIdx.x == 0) atomicAdd(loss_acc, red[0] + red[1] + red[2] + red[3]);
}

// ---------------------------------------------------------------------------
#define CHUNK 8192
__global__ __launch_bounds__(1024) void stats_kernel(const float* __restrict__ z,
                                                     const int* __restrict__ idx,
                                                     const float* __restrict__ N_t,
                                                     const float* __restrict__ m_t,
                                                     float* __restrict__ outN,
                                                     float* __restrict__ outM,
                                                     float* __restrict__ counts) {
    const int j = blockIdx.x;
    __shared__ int list[CHUNK];
    __shared__ int cnt_s;
    __shared__ float red[16 * 256];
    const int tid = threadIdx.x, w = tid >> 6, lane = tid & 63;
    float4 acc = make_float4(0.f, 0.f, 0.f, 0.f);
    int total = 0;
    for (int c = 0; c < N_ROWS; c += CHUNK) {
        if (tid == 0) cnt_s = 0;
        __syncthreads();
        #pragma unroll
        for (int i = 0; i < CHUNK / 1024; ++i) {
            int p = c + tid + i * 1024;
            if (idx[p] == j) { int s = atomicAdd(&cnt_s, 1); list[s] = p; }
        }
        __syncthreads();
        int m = cnt_s;
        total += m;
        for (int e = w; e < m; e += 16) {
            float4 v = ((const float4*)(z + (size_t)list[e] * EDIM))[lane];
            acc.x += v.x; acc.y += v.y; acc.z += v.z; acc.w += v.w;
        }
        __syncthreads();
    }
    *(float4*)(red + w * 256 + lane * 4) = acc;
    __syncthreads();
    if (tid < 256) {
        float s = 0.f;
        #pragma unroll
        for (int ww = 0; ww < 16; ++ww) s += red[ww * 256 + tid];
        float mold = m_t[(size_t)j * EDIM + tid];
        outM[(size_t)j * EDIM + tid] = (total > 0) ? mold * LAMBDA + s * (1.0f - LAMBDA) : mold;
    }
    if (tid == 0) {
        float Nold = N_t[j];
        outN[j] = (total > 0) ? Nold * LAMBDA + (float)total * (1.0f - LAMBDA) : Nold;
        counts[j] = (float)total;
    }
}

// ---------------------------------------------------------------------------
__global__ __launch_bounds__(256) void final_kernel(const float* __restrict__ counts,
                                                    const float* __restrict__ loss_acc,
                                                    float* __restrict__ out_loss,
                                                    float* __restrict__ out_perp) {
    const int tid = threadIdx.x, w = tid >> 6, lane = tid & 63;
    float h = 0.f;
    for (int c = tid; c < NE; c += 256) {
        float em = counts[c] * (1.0f / (float)N_ROWS);
        h += em * logf(em + 1e-10f);
    }
    #pragma unroll
    for (int m = 32; m; m >>= 1) h += __shfl_down(h, m);
    __shared__ float red[4];
    if (lane == 0) red[w] = h;
    __syncthreads();
    if (tid == 0) {
        float H = red[0] + red[1] + red[2] + red[3];
        out_perp[0] = expf(-H);
        out_loss[0] = BETA * loss_acc[0] * (1.0f / (float)(N_ROWS * EDIM));
    }
}

// ---------------------------------------------------------------------------
extern "C" void kernel_launch(void* const* d_in, const int* in_sizes, int n_in,
                              void* d_out, int out_size, void* d_ws, size_t ws_size,
                              hipStream_t stream) {
    const float* z   = (const float*)d_in[0];
    const float* emb = (const float*)d_in[1];
    const float* N_t = (const float*)d_in[2];
    const float* m_t = (const float*)d_in[3];
    float* out = (float*)d_out;
    float* ws  = (float*)d_ws;

    float*  loss_acc = ws;
    int*    flag_cnt = (int*)(ws + 1);
    float*  e_sq     = ws + 64;
    float*  counts   = ws + 1088;
    float*  e_t      = ws + 2048;
    ushort* Bhi      = (ushort*)(ws + 264192);
    ushort* Blo      = (ushort*)(ws + 395264);
    int*    idx1     = (int*)(ws + 526336);
    int*    flags    = (int*)(ws + 591872);
    float4* partial  = (float4*)(ws + 657408);

    prep_kernel<<<NE, 64, 0, stream>>>(emb, e_t, Bhi, Blo, loss_acc, flag_cnt);
    sq_kernel<<<NE / 16, 256, 0, stream>>>(emb, e_sq);
    mfma_kernel<<<(N_ROWS / 128) * 8, 256, 0, stream>>>(z, Bhi, Blo, e_sq, partial);
    reduce_kernel<<<N_ROWS / 256, 256, 0, stream>>>(partial, idx1, flags, flag_cnt);
    resolve_kernel<<<512, 256, 0, stream>>>(z, e_t, e_sq, flags, flag_cnt, idx1);
    gather_kernel<<<N_ROWS / 4, 256, 0, stream>>>(z, emb, idx1, out + O_ZQ, out + O_IDX, loss_acc);
    stats_kernel<<<NE, 1024, 0, stream>>>(z, idx1, N_t, m_t, out + O_NT, out + O_MT, counts);
    final_kernel<<<1, 256, 0, stream>>>(counts, loss_acc, out + 0, out + O_PERP);
}

// Round 6
// 975.132 us; speedup vs baseline: 1.0790x; 1.0790x over previous
//
#include <hip/hip_runtime.h>
#include <math.h>
#include <float.h>

#define N_ROWS  65536
#define EDIM    256
#define NE      1024
#define BETA    0.25f
#define LAMBDA  0.99f
#define EPS     1.5e-4f

// ---------------- ws layout (float units) ----------------
// [0] loss_acc  [1] flag_cnt(int)
// [64]     e_sq[1024]
// [1088]   counts[1024]
// [2048]   e_t[256*1024]           (1 MB, for resolve)
// [264192] Bhi ushort[1024*256]    (512 KB)
// [395264] Blo ushort[1024*256]
// [526336] idx[65536] (int)
// [591872] flags[65536] (int)
// total ~2.6 MB

#define O_ZQ   1
#define O_IDX  16777217
#define O_PERP 16842753
#define O_NT   16842754
#define O_MT   16843778

typedef short  bf16x8 __attribute__((ext_vector_type(8)));
typedef float  f32x4  __attribute__((ext_vector_type(4)));

__device__ __forceinline__ ushort f2bf(float x) {
    unsigned u = __float_as_uint(x);
    return (ushort)((u + 0x7FFFu + ((u >> 16) & 1u)) >> 16);
}
__device__ __forceinline__ float bf2f(ushort h) {
    return __uint_as_float(((unsigned)h) << 16);
}

// ---------------------------------------------------------------------------
// prep: e_t transpose (for resolve), Bhi/Blo split-bf16, zero accumulators
__global__ __launch_bounds__(64) void prep_kernel(const float* __restrict__ emb,
                                                  float* __restrict__ e_t,
                                                  ushort* __restrict__ Bhi,
                                                  ushort* __restrict__ Blo,
                                                  float* __restrict__ loss_acc,
                                                  int* __restrict__ flag_cnt) {
    int j = blockIdx.x, l = threadIdx.x;
    float4 v = ((const float4*)(emb + j * EDIM))[l];
    int k = 4 * l;
    e_t[(k + 0) * NE + j] = v.x;
    e_t[(k + 1) * NE + j] = v.y;
    e_t[(k + 2) * NE + j] = v.z;
    e_t[(k + 3) * NE + j] = v.w;
    float f[4] = {v.x, v.y, v.z, v.w};
    ushort h[4], lo[4];
    #pragma unroll
    for (int i = 0; i < 4; ++i) { h[i] = f2bf(f[i]); lo[i] = f2bf(f[i] - bf2f(h[i])); }
    uint2 ph = make_uint2((uint)h[0] | ((uint)h[1] << 16), (uint)h[2] | ((uint)h[3] << 16));
    uint2 pl = make_uint2((uint)lo[0] | ((uint)lo[1] << 16), (uint)lo[2] | ((uint)lo[3] << 16));
    *(uint2*)(Bhi + j * EDIM + k) = ph;
    *(uint2*)(Blo + j * EDIM + k) = pl;
    if (j == 0 && l == 0) { *loss_acc = 0.0f; *flag_cnt = 0; }
}

// ---------------------------------------------------------------------------
// sq_kernel: numpy-pairwise-exact fp32 sum of squares (row of 256)
__global__ __launch_bounds__(256) void sq_kernel(const float* __restrict__ src,
                                                 float* __restrict__ dst) {
    const int tid = threadIdx.x;
    const int row = blockIdx.x * 16 + (tid >> 4);
    const int q = tid & 15, h = q >> 3, j = q & 7;
    const float* __restrict__ p = src + (size_t)row * EDIM + h * 128 + j;
    float acc = __fmul_rn(p[0], p[0]);
    #pragma unroll
    for (int t = 1; t < 16; ++t) { float v = p[8 * t]; acc = __fadd_rn(acc, __fmul_rn(v, v)); }
    acc = __fadd_rn(acc, __shfl_xor(acc, 1));
    acc = __fadd_rn(acc, __shfl_xor(acc, 2));
    acc = __fadd_rn(acc, __shfl_xor(acc, 4));
    acc = __fadd_rn(acc, __shfl_xor(acc, 8));
    if (q == 0) dst[row] = acc;
}

// ---------------------------------------------------------------------------
__device__ __forceinline__ void merge2(float& v1, int& i1, float& v2, int& i2,
                                       float w1, int j1, float w2, int j2) {
    bool w1best = (w1 < v1) || (w1 == v1 && j1 < i1);
    if (w1best) {
        bool keep = (v1 < w2) || (v1 == w2 && i1 < j2);
        v2 = keep ? v1 : w2; i2 = keep ? i1 : j2;
        v1 = w1; i1 = j1;
    } else {
        bool rep = (w1 < v2) || (w1 == v2 && j1 < i2);
        if (rep) { v2 = w1; i2 = j1; }
    }
}
__device__ __forceinline__ void ins2(float& v1, int& i1, float& v2, int& i2,
                                     float s, int c) {
    if (s < v1 || (s == v1 && c < i1)) { v2 = v1; i2 = i1; v1 = s; i1 = c; }
    else if (s < v2 || (s == v2 && c < i2)) { v2 = s; i2 = c; }
}

// ---------------------------------------------------------------------------
// mfma_kernel: 128-row stripe per block, z converted ONCE to full-K-resident
// hi/lo bf16 LDS A; loop over all 8 col-blocks staging only 16 KB B tiles.
// 3 MFMA passes (hh+hl+lh). Per-nb top-2 epilogue merges into rtop[128];
// final: idx + flag (gap < EPS -> exact re-resolve later).
#define LDA 264     // ushorts per A row (256 + 8 pad: 16B-aligned rows)
__global__ __launch_bounds__(512) void mfma_kernel(const float* __restrict__ z,
                                                   const ushort* __restrict__ Bhi,
                                                   const ushort* __restrict__ Blo,
                                                   const float* __restrict__ e_sq,
                                                   int* __restrict__ idx_out,
                                                   int* __restrict__ flags,
                                                   int* __restrict__ flag_cnt) {
    __shared__ __align__(16) ushort sAh[128 * LDA];   // 66 KB
    __shared__ __align__(16) ushort sAl[128 * LDA];   // 66 KB
    __shared__ __align__(16) ushort sBh[128 * 32];    // 8 KB
    __shared__ __align__(16) ushort sBl[128 * 32];    // 8 KB
    __shared__ float4 pt[256];                        // 4 KB
    __shared__ float4 rtop[128];                      // 2 KB

    const int tid  = threadIdx.x;
    const int row0 = blockIdx.x * 128;
    const int wave = tid >> 6, lane = tid & 63;
    const int wr = wave >> 1, wc = wave & 1;          // 4 row-groups x 2 col-halves
    const int lquad = lane >> 4, l16 = lane & 15;

    // ---- stage + convert A once: 128 rows x 256 k, fp32 -> hi/lo bf16 ----
    {
        const float4* __restrict__ zb4 = (const float4*)(z + (size_t)row0 * EDIM);
        #pragma unroll
        for (int i = 0; i < 16; ++i) {
            int g = tid + i * 512;            // float4 index within stripe
            int r = g >> 6;                   // row
            int kk = (g & 63) * 4;            // k
            float4 f = zb4[g];
            ushort4 H = make_ushort4(f2bf(f.x), f2bf(f.y), f2bf(f.z), f2bf(f.w));
            ushort4 L = make_ushort4(f2bf(f.x - bf2f(H.x)), f2bf(f.y - bf2f(H.y)),
                                     f2bf(f.z - bf2f(H.z)), f2bf(f.w - bf2f(H.w)));
            *(ushort4*)(sAh + r * LDA + kk) = H;
            *(ushort4*)(sAl + r * LDA + kk) = L;
        }
    }
    if (tid < 128)
        rtop[tid] = make_float4(FLT_MAX, FLT_MAX,
                                __int_as_float(0x7fffffff), __int_as_float(0x7fffffff));
    __syncthreads();

    for (int nb = 0; nb < 8; ++nb) {
        const int col0 = nb * 128;
        f32x4 acc[2][4];
        #pragma unroll
        for (int mi = 0; mi < 2; ++mi)
            #pragma unroll
            for (int ni = 0; ni < 4; ++ni) acc[mi][ni] = (f32x4)0.0f;

        for (int k0 = 0; k0 < EDIM; k0 += 32) {
            __syncthreads();   // prior consumers of sB done
            {   // stage B tile [128 cols][32 k], hi+lo: 1 uint4 per thread each
                const int col = tid >> 2, part = tid & 3;
                size_t off = (size_t)(col0 + col) * EDIM + k0 + part * 8;
                *(uint4*)(sBh + col * 32 + part * 8) = *(const uint4*)(Bhi + off);
                *(uint4*)(sBl + col * 32 + part * 8) = *(const uint4*)(Blo + off);
            }
            __syncthreads();

            bf16x8 ah[2], al[2], bh[4], bl[4];
            #pragma unroll
            for (int mi = 0; mi < 2; ++mi) {
                int m = wr * 32 + mi * 16 + l16;
                ah[mi] = *(const bf16x8*)(sAh + m * LDA + k0 + lquad * 8);
                al[mi] = *(const bf16x8*)(sAl + m * LDA + k0 + lquad * 8);
            }
            #pragma unroll
            for (int ni = 0; ni < 4; ++ni) {
                int n = wc * 64 + ni * 16 + l16;
                bh[ni] = *(const bf16x8*)(sBh + n * 32 + lquad * 8);
                bl[ni] = *(const bf16x8*)(sBl + n * 32 + lquad * 8);
            }
            #pragma unroll
            for (int mi = 0; mi < 2; ++mi)
                #pragma unroll
                for (int ni = 0; ni < 4; ++ni) {
                    acc[mi][ni] = __builtin_amdgcn_mfma_f32_16x16x32_bf16(ah[mi], bh[ni], acc[mi][ni], 0, 0, 0);
                    acc[mi][ni] = __builtin_amdgcn_mfma_f32_16x16x32_bf16(ah[mi], bl[ni], acc[mi][ni], 0, 0, 0);
                    acc[mi][ni] = __builtin_amdgcn_mfma_f32_16x16x32_bf16(al[mi], bh[ni], acc[mi][ni], 0, 0, 0);
                }
        }

        // ---- epilogue for this nb: s = esq - 2*dot, per-row top-2 over 128 cols
        float eq[4]; int cidx[4];
        #pragma unroll
        for (int ni = 0; ni < 4; ++ni) {
            cidx[ni] = col0 + wc * 64 + ni * 16 + l16;
            eq[ni] = e_sq[cidx[ni]];
        }
        #pragma unroll
        for (int mi = 0; mi < 2; ++mi) {
            #pragma unroll
            for (int reg = 0; reg < 4; ++reg) {
                float v1 = FLT_MAX, v2 = FLT_MAX; int i1 = 0x7fffffff, i2 = 0x7fffffff;
                #pragma unroll
                for (int ni = 0; ni < 4; ++ni) {
                    float s = fmaf(-2.0f, acc[mi][ni][reg], eq[ni]);
                    ins2(v1, i1, v2, i2, s, cidx[ni]);
                }
                // C/D: col = lane&15, row = (lane>>4)*4 + reg
                #pragma unroll
                for (int m = 1; m < 16; m <<= 1) {
                    float w1 = __shfl_xor(v1, m), w2 = __shfl_xor(v2, m);
                    int   j1 = __shfl_xor(i1, m), j2 = __shfl_xor(i2, m);
                    merge2(v1, i1, v2, i2, w1, j1, w2, j2);
                }
                if (l16 == 0) {
                    int row = wr * 32 + mi * 16 + lquad * 4 + reg;
                    pt[wc * 128 + row] = make_float4(v1, v2, __int_as_float(i1), __int_as_float(i2));
                }
            }
        }
        __syncthreads();
        if (tid < 128) {
            float4 a = pt[tid], b = pt[128 + tid];
            float v1 = a.x, v2 = a.y; int i1 = __float_as_int(a.z), i2 = __float_as_int(a.w);
            merge2(v1, i1, v2, i2, b.x, __float_as_int(b.z), b.y, __float_as_int(b.w));
            float4 r = rtop[tid];
            float rv1 = r.x, rv2 = r.y; int ri1 = __float_as_int(r.z), ri2 = __float_as_int(r.w);
            merge2(rv1, ri1, rv2, ri2, v1, i1, v2, i2);
            rtop[tid] = make_float4(rv1, rv2, __int_as_float(ri1), __int_as_float(ri2));
        }
        // next iteration's leading __syncthreads() protects pt reuse
    }
    __syncthreads();
    if (tid < 128) {
        float4 t = rtop[tid];
        int grow = row0 + tid;
        int i1 = __float_as_int(t.z);
        idx_out[grow] = i1;
        if (t.y - t.x < EPS) { int p = atomicAdd(flag_cnt, 1); flags[p] = grow; }
    }
}

// ---------------------------------------------------------------------------
// resolve: exact fp32 (numpy-semantics) full-row argmin for flagged rows.
// Pipelined: float4 zrow + 4 e_t float4 loads per step, unroll 4.
__global__ __launch_bounds__(256) void resolve_kernel(const float* __restrict__ z,
                                                      const float* __restrict__ e_t,
                                                      const float* __restrict__ e_sq,
                                                      const int* __restrict__ flags,
                                                      const int* __restrict__ flag_cnt,
                                                      int* __restrict__ idx_out) {
    __shared__ float zrow[EDIM];
    __shared__ float zsq_s;
    __shared__ float wv[4]; __shared__ int wi[4];
    const int tid = threadIdx.x, wave = tid >> 6, lane = tid & 63;
    const int cnt = *flag_cnt;
    for (int f = blockIdx.x; f < cnt; f += gridDim.x) {
        const int row = flags[f];
        __syncthreads();
        zrow[tid] = z[(size_t)row * EDIM + tid];
        __syncthreads();
        if (tid < 16) {   // numpy-pairwise-exact zsq
            const int h = tid >> 3, j = tid & 7;
            const float* p = zrow + h * 128 + j;
            float a = __fmul_rn(p[0], p[0]);
            #pragma unroll
            for (int t = 1; t < 16; ++t) { float v = p[8 * t]; a = __fadd_rn(a, __fmul_rn(v, v)); }
            a = __fadd_rn(a, __shfl_xor(a, 1));
            a = __fadd_rn(a, __shfl_xor(a, 2));
            a = __fadd_rn(a, __shfl_xor(a, 4));
            a = __fadd_rn(a, __shfl_xor(a, 8));
            if (tid == 0) zsq_s = a;
        }
        __syncthreads();
        const float zq = zsq_s;
        const float* __restrict__ et = e_t + 4 * tid;
        float acc0 = 0.f, acc1 = 0.f, acc2 = 0.f, acc3 = 0.f;
        #pragma unroll 4
        for (int k = 0; k < EDIM; k += 4) {   // exact sequential-k fma chain
            float4 zk = *(const float4*)(zrow + k);
            float4 e0 = *(const float4*)(et + (size_t)(k + 0) * NE);
            float4 e1 = *(const float4*)(et + (size_t)(k + 1) * NE);
            float4 e2 = *(const float4*)(et + (size_t)(k + 2) * NE);
            float4 e3 = *(const float4*)(et + (size_t)(k + 3) * NE);
            acc0 = fmaf(zk.x, e0.x, acc0); acc1 = fmaf(zk.x, e0.y, acc1);
            acc2 = fmaf(zk.x, e0.z, acc2); acc3 = fmaf(zk.x, e0.w, acc3);
            acc0 = fmaf(zk.y, e1.x, acc0); acc1 = fmaf(zk.y, e1.y, acc1);
            acc2 = fmaf(zk.y, e1.z, acc2); acc3 = fmaf(zk.y, e1.w, acc3);
            acc0 = fmaf(zk.z, e2.x, acc0); acc1 = fmaf(zk.z, e2.y, acc1);
            acc2 = fmaf(zk.z, e2.z, acc2); acc3 = fmaf(zk.z, e2.w, acc3);
            acc0 = fmaf(zk.w, e3.x, acc0); acc1 = fmaf(zk.w, e3.y, acc1);
            acc2 = fmaf(zk.w, e3.z, acc2); acc3 = fmaf(zk.w, e3.w, acc3);
        }
        float av[4] = {acc0, acc1, acc2, acc3};
        float bv = FLT_MAX; int bi = 0x7fffffff;
        #pragma unroll
        for (int c = 0; c < 4; ++c) {
            int col = 4 * tid + c;
            float d = __fsub_rn(__fadd_rn(zq, e_sq[col]), __fmul_rn(2.0f, av[c]));
            if (d < bv || (d == bv && col < bi)) { bv = d; bi = col; }
        }
        #pragma unroll
        for (int m = 1; m < 64; m <<= 1) {
            float v = __shfl_xor(bv, m); int i = __shfl_xor(bi, m);
            if (v < bv || (v == bv && i < bi)) { bv = v; bi = i; }
        }
        if (lane == 0) { wv[wave] = bv; wi[wave] = bi; }
        __syncthreads();
        if (tid == 0) {
            #pragma unroll
            for (int w = 1; w < 4; ++w)
                if (wv[w] < bv || (wv[w] == bv && wi[w] < bi)) { bv = wv[w]; bi = wi[w]; }
            idx_out[row] = bi;
        }
    }
}

// ---------------------------------------------------------------------------
__global__ __launch_bounds__(256) void gather_kernel(const float* __restrict__ z,
                                                     const float* __restrict__ emb,
                                                     const int* __restrict__ idx,
                                                     float* __restrict__ out_zq,
                                                     float* __restrict__ out_idx,
                                                     float* __restrict__ loss_acc) {
    int sub = threadIdx.x >> 6, lane = threadIdx.x & 63;
    int row = blockIdx.x * 4 + sub;
    int id = idx[row];
    float4 e = ((const float4*)(emb + (size_t)id * EDIM))[lane];
    float4 zv = ((const float4*)(z + (size_t)row * EDIM))[lane];
    float* o = out_zq + (size_t)row * EDIM + lane * 4;
    o[0] = e.x; o[1] = e.y; o[2] = e.z; o[3] = e.w;
    float dx = e.x - zv.x, dy = e.y - zv.y, dz = e.z - zv.z, dw = e.w - zv.w;
    float lp = dx * dx + dy * dy + dz * dz + dw * dw;
    #pragma unroll
    for (int m = 32; m; m >>= 1) lp += __shfl_down(lp, m);
    __shared__ float red[4];
    if (lane == 0) { red[sub] = lp; out_idx[row] = (float)id; }
    __syncthreads();
    if (threadIdx.x == 0) atomicAdd(loss_acc, red[0] + red[1] + red[2] + red[3]);
}

// ---------------------------------------------------------------------------
#define CHUNK 8192
__global__ __launch_bounds__(1024) void stats_kernel(const float* __restrict__ z,
                                                     const int* __restrict__ idx,
                                                     const float* __restrict__ N_t,
                                                     const float* __restrict__ m_t,
                                                     float* __restrict__ outN,
                                                     float* __restrict__ outM,
                                                     float* __restrict__ counts) {
    const int j = blockIdx.x;
    __shared__ int list[CHUNK];
    __shared__ int cnt_s;
    __shared__ float red[16 * 256];
    const int tid = threadIdx.x, w = tid >> 6, lane = tid & 63;
    float4 acc = make_float4(0.f, 0.f, 0.f, 0.f);
    int total = 0;
    for (int c = 0; c < N_ROWS; c += CHUNK) {
        if (tid == 0) cnt_s = 0;
        __syncthreads();
        #pragma unroll
        for (int i = 0; i < CHUNK / 1024; ++i) {
            int p = c + tid + i * 1024;
            if (idx[p] == j) { int s = atomicAdd(&cnt_s, 1); list[s] = p; }
        }
        __syncthreads();
        int m = cnt_s;
        total += m;
        for (int e = w; e < m; e += 16) {
            float4 v = ((const float4*)(z + (size_t)list[e] * EDIM))[lane];
            acc.x += v.x; acc.y += v.y; acc.z += v.z; acc.w += v.w;
        }
        __syncthreads();
    }
    *(float4*)(red + w * 256 + lane * 4) = acc;
    __syncthreads();
    if (tid < 256) {
        float s = 0.f;
        #pragma unroll
        for (int ww = 0; ww < 16; ++ww) s += red[ww * 256 + tid];
        float mold = m_t[(size_t)j * EDIM + tid];
        outM[(size_t)j * EDIM + tid] = (total > 0) ? mold * LAMBDA + s * (1.0f - LAMBDA) : mold;
    }
    if (tid == 0) {
        float Nold = N_t[j];
        outN[j] = (total > 0) ? Nold * LAMBDA + (float)total * (1.0f - LAMBDA) : Nold;
        counts[j] = (float)total;
    }
}

// ---------------------------------------------------------------------------
__global__ __launch_bounds__(256) void final_kernel(const float* __restrict__ counts,
                                                    const float* __restrict__ loss_acc,
                                                    float* __restrict__ out_loss,
                                                    float* __restrict__ out_perp) {
    const int tid = threadIdx.x, w = tid >> 6, lane = tid & 63;
    float h = 0.f;
    for (int c = tid; c < NE; c += 256) {
        float em = counts[c] * (1.0f / (float)N_ROWS);
        h += em * logf(em + 1e-10f);
    }
    #pragma unroll
    for (int m = 32; m; m >>= 1) h += __shfl_down(h, m);
    __shared__ float red[4];
    if (lane == 0) red[w] = h;
    __syncthreads();
    if (tid == 0) {
        float H = red[0] + red[1] + red[2] + red[3];
        out_perp[0] = expf(-H);
        out_loss[0] = BETA * loss_acc[0] * (1.0f / (float)(N_ROWS * EDIM));
    }
}

// ---------------------------------------------------------------------------
extern "C" void kernel_launch(void* const* d_in, const int* in_sizes, int n_in,
                              void* d_out, int out_size, void* d_ws, size_t ws_size,
                              hipStream_t stream) {
    const float* z   = (const float*)d_in[0];
    const float* emb = (const float*)d_in[1];
    const float* N_t = (const float*)d_in[2];
    const float* m_t = (const float*)d_in[3];
    float* out = (float*)d_out;
    float* ws  = (float*)d_ws;

    float*  loss_acc = ws;
    int*    flag_cnt = (int*)(ws + 1);
    float*  e_sq     = ws + 64;
    float*  counts   = ws + 1088;
    float*  e_t      = ws + 2048;
    ushort* Bhi      = (ushort*)(ws + 264192);
    ushort* Blo      = (ushort*)(ws + 395264);
    int*    idx1     = (int*)(ws + 526336);
    int*    flags    = (int*)(ws + 591872);

    prep_kernel<<<NE, 64, 0, stream>>>(emb, e_t, Bhi, Blo, loss_acc, flag_cnt);
    sq_kernel<<<NE / 16, 256, 0, stream>>>(emb, e_sq);
    mfma_kernel<<<N_ROWS / 128, 512, 0, stream>>>(z, Bhi, Blo, e_sq, idx1, flags, flag_cnt);
    resolve_kernel<<<2048, 256, 0, stream>>>(z, e_t, e_sq, flags, flag_cnt, idx1);
    gather_kernel<<<N_ROWS / 4, 256, 0, stream>>>(z, emb, idx1, out + O_ZQ, out + O_IDX, loss_acc);
    stats_kernel<<<NE, 1024, 0, stream>>>(z, idx1, N_t, m_t, out + O_NT, out + O_MT, counts);
    final_kernel<<<1, 256, 0, stream>>>(counts, loss_acc, out + 0, out + O_PERP);
}